// Round 6
// baseline (603.700 us; speedup 1.0000x reference)
//
#include <hip/hip_runtime.h>
#include <hip/hip_bf16.h>

// Problem constants
#define BROWS 8192      // B*N = 8*1024
#define DDIM 3
#define CDIM 64
#define KF 8192         // F = 2*C*C
#define NINV 512
#define NEQ 1024        // per head
#define NTOT 2560       // 512 + 1024 + 1024
#define BAS 16
#define UEQ 64

// Packed-tile layouts (producers and GEMM agree):
//  A: tile (mb, kt) = 256 rows x 32 k bf16 = 16 KB at byte ((mb*256+kt) << 14)
//  B: tile (nb, kt) = 320 rows x 32 k bf16 = 20 KB at byte ((nb*256+kt) * 20480)
//  Within a tile, element (rloc, kk):
//    logical chunk lc = (kk>>3)&3, phys = (lc + (rloc>>1)) & 3  (bank swizzle)
//    byte = rloc*64 + phys*16 + (kk&7)*2
// Staging is a linear memcpy per tile.

typedef float f32x4 __attribute__((ext_vector_type(4)));
typedef __bf16 bf16x8_t __attribute__((ext_vector_type(8)));
typedef __bf16 bf16x4_t __attribute__((ext_vector_type(4)));

__device__ __forceinline__ void async_copy16(const void* g, void* l) {
    __builtin_amdgcn_global_load_lds(
        (__attribute__((address_space(1))) void*)(g),
        (__attribute__((address_space(3))) void*)(l), 16, 0, 0);
}

// ---------------------------------------------------------------------------
// Kernel 1: per-row l2norm + Gram blocks -> packed feats tiles [32][256][16KB]
// R4: 16 rows/block, wave-coalesced 1KB burst stores (R4 win: -36 us total).
// ---------------------------------------------------------------------------
#define FROWS 16
#define FSTRIDE 196

__global__ __launch_bounds__(256) void feats_kernel(
    const float* __restrict__ t1, const float* __restrict__ t2,
    const float* __restrict__ u1, const float* __restrict__ u2,
    __hip_bfloat16* __restrict__ feats)
{
    __shared__ float sT1[FROWS * FSTRIDE];
    __shared__ float sT2[FROWS * FSTRIDE];
    __shared__ float sU1[FROWS * FSTRIDE];
    __shared__ float sU2[FROWS * FSTRIDE];

    const int tid = threadIdx.x;
    const int r0  = blockIdx.x * FROWS;          // first row of this block

    // Phase 1: stage T,U (16 rows x 192 floats x 4 arrays), coalesced.
    #pragma unroll
    for (int k = 0; k < 12; ++k) {
        const int item = k * 256 + tid;          // < 3072
        const int r = item / 192, c = item - r * 192;
        const size_t g = (size_t)(r0 + r) * 192 + c;
        const int l = r * FSTRIDE + c;
        sT1[l] = t1[g];
        sT2[l] = t2[g];
        sU1[l] = u1[g];
        sU2[l] = u2[g];
    }
    __syncthreads();

    // Phase 2: l2-normalize U over d, per (row, head, c). 2048 items.
    #pragma unroll
    for (int k = 0; k < 8; ++k) {
        const int item = k * 256 + tid;          // < 2048
        const int r = item >> 7, rem = item & 127;
        const int h = rem >> 6, c = rem & 63;
        float* U = (h ? sU2 : sU1) + r * FSTRIDE;
        float sq = U[c] * U[c] + U[64 + c] * U[64 + c] + U[128 + c] * U[128 + c];
        float s = 1.0f / sqrtf(fmaxf(sq, 0.01f));
        U[c] *= s; U[64 + c] *= s; U[128 + c] *= s;
    }
    __syncthreads();

    // Phase 3: Gram compute + coalesced packed stores.
    const int w       = tid >> 6;        // wave 0..3 -> kt block
    const int lane    = tid & 63;
    const int r_local = lane >> 2;       // 0..15
    const int p       = lane & 3;        // phys chunk
    const int mb      = r0 >> 8;
    const int rloc0   = r0 & 255;
    const int rloc    = rloc0 + r_local;
    const int lc      = (p - (rloc >> 1)) & 3;   // invert phys swizzle
    const float* Tarr = (w >= 2 ? sT2 : sT1) + r_local * FSTRIDE;
    const float* Uarr = (w >= 2 ? sU2 : sU1) + r_local * FSTRIDE;

    char* dst = (char*)feats + (((size_t)(mb * 256 + w * 64)) << 14)
              + rloc0 * 64 + lane * 16;

    #pragma unroll 4
    for (int it = 0; it < 64; ++it) {
        const int kt = w * 64 + it;
        const int i  = (kt >> 1) & 63;
        const int jh = (kt & 1) * 32;
        const int j0 = jh + lc * 8;
        const float ti0 = Tarr[i], ti1 = Tarr[64 + i], ti2 = Tarr[128 + i];
        bf16x8_t vv;
        #pragma unroll
        for (int half = 0; half < 2; ++half) {
            const int j = j0 + half * 4;
            const float4 u0 = *reinterpret_cast<const float4*>(Uarr + j);
            const float4 u1_ = *reinterpret_cast<const float4*>(Uarr + 64 + j);
            const float4 u2_ = *reinterpret_cast<const float4*>(Uarr + 128 + j);
            vv[half * 4 + 0] = (__bf16)(ti0 * u0.x + ti1 * u1_.x + ti2 * u2_.x);
            vv[half * 4 + 1] = (__bf16)(ti0 * u0.y + ti1 * u1_.y + ti2 * u2_.y);
            vv[half * 4 + 2] = (__bf16)(ti0 * u0.z + ti1 * u1_.z + ti2 * u2_.z);
            vv[half * 4 + 3] = (__bf16)(ti0 * u0.w + ti1 * u1_.w + ti2 * u2_.w);
        }
        *reinterpret_cast<bf16x8_t*>(dst) = vv;   // 64 lanes x 16B = 1KB burst
        dst += 16384;
    }
}

// ---------------------------------------------------------------------------
// Kernel 2: transpose+convert W (K x N fp32) -> packed WT tiles [8][256][20KB]
// ---------------------------------------------------------------------------
__global__ __launch_bounds__(256) void wt_kernel(
    const float* __restrict__ W_inv, const float* __restrict__ W_eq,
    __hip_bfloat16* __restrict__ WT)
{
    __shared__ float tile[32][33];
    const int tid = threadIdx.x;
    const int tx = tid & 31;          // n within tile (load)
    const int ty = tid >> 5;          // 0..7
    const int n0 = blockIdx.x * 32;   // output column block (0..2559)
    const int k0 = blockIdx.y * 32;   // K block (0..8191)

    const float* src; int ldn, nl0;
    if (n0 < NINV)            { src = W_inv;                       ldn = NINV; nl0 = n0; }
    else if (n0 < NINV + NEQ) { src = W_eq;                        ldn = NEQ;  nl0 = n0 - NINV; }
    else                      { src = W_eq + (size_t)KF * NEQ;     ldn = NEQ;  nl0 = n0 - NINV - NEQ; }

    #pragma unroll
    for (int i = 0; i < 4; ++i) {
        int kl = ty + i * 8;
        tile[kl][tx] = src[(size_t)(k0 + kl) * ldn + nl0 + tx];
    }
    __syncthreads();
    // store phase: each thread packs 4 consecutive k for one n (8 B store)
    const int n_l = tid >> 3;         // 0..31
    const int k4  = (tid & 7) * 4;    // 0..28
    bf16x4_t v;
    #pragma unroll
    for (int q = 0; q < 4; ++q) v[q] = (__bf16)tile[k4 + q][n_l];

    const int n    = n0 + n_l;
    const int nb   = n / 320, rloc = n - nb * 320;
    const int kt   = k0 >> 5;
    const int lc   = (k4 >> 3) & 3, e = k4 & 7;
    const int phys = (lc + (rloc >> 1)) & 3;
    char* dst = (char*)WT + ((size_t)(nb * 256 + kt)) * 20480
              + rloc * 64 + phys * 16 + e * 2;
    *reinterpret_cast<bf16x4_t*>(dst) = v;
}

// ---------------------------------------------------------------------------
// Kernel 3: bf16 MFMA GEMM on packed tiles + FUSED eq-recombine epilogue (R5).
// BM=256 x BN=320, 256 blocks (1/CU), 512 threads = 8 waves (4m x 2n).
// R5: eqcomb fused — for eq columns each 16-lane group holds one unit's 16
//     basis values; V for the block's 256 rows is staged into the (dead) GEMM
//     LDS after the last COMPUTE, and out_eq = 16-lane shfl_xor butterfly.
//     Deletes Yeq (67MB w + 67MB r) and the 4th kernel.
// ---------------------------------------------------------------------------
#define BM 256
#define BN 320
#define BK 32
#define ATILE 16384
#define BTILE 20480

__global__ __launch_bounds__(512, 2) void gemm_kernel(
    const __hip_bfloat16* __restrict__ A,   // packed [32][256][16KB]
    const __hip_bfloat16* __restrict__ BT,  // packed [8][256][20KB]
    const float* __restrict__ b_inv, const float* __restrict__ g_inv,
    const float* __restrict__ be_inv,
    const float* __restrict__ b_eq,  const float* __restrict__ g_eq,
    const float* __restrict__ be_eq,
    const float* __restrict__ V1,   const float* __restrict__ V2,
    float* __restrict__ out_inv,            // d_out: [BROWS][NINV]
    float* __restrict__ out_eq)             // d_out: [BROWS][3][128]
{
    __shared__ alignas(16) char smem[147456];
    auto* AsBuf = reinterpret_cast<__hip_bfloat16(*)[BM * BK]>(smem);           // 4 x 16 KB
    auto* BsBuf = reinterpret_cast<__hip_bfloat16(*)[BN * BK]>(smem + 65536);   // 4 x 20 KB
    float* sV   = reinterpret_cast<float*>(smem);  // reused after last COMPUTE
    // sV layout: [head][m][row 0..255][17] floats (pad 16->17 staggers banks)

    const int tid  = threadIdx.x;
    const int wave = tid >> 6;
    const int lane = tid & 63;
    const bool aWave = wave < 4;

    // 256 blocks: xcd = b%8 owns 4 contiguous m-stripes, n fastest.
    const int b    = blockIdx.x;
    const int xcd  = b & 7;
    const int slot = b >> 3;            // 0..31
    const int nb   = slot & 7;          // 0..7
    const int mb   = xcd * 4 + (slot >> 3);
    const int n0   = nb * BN;
    const int m0   = mb * BM;

    const char* pA = (const char*)A  + ((size_t)mb << 22);        // mb*4MB
    const char* pB = (const char*)BT + (size_t)nb * 256 * BTILE;  // nb*5MB

    // staging offsets (linear memcpy within a tile)
    const int aoff = wave * 4096 + lane * 16;         // waves 0-3
    const int boff = (wave - 4) * 5120 + lane * 16;   // waves 4-7

    // ds_read chunk swizzle (row-parity based, tile-term-independent)
    const int chnk = (((lane >> 4) + ((lane & 15) >> 1)) & 3) * 8;
    const int wm = (wave & 3) * 64;
    const int wn = (wave >> 2) * 160;
    const int l15 = lane & 15;
    const int q   = lane >> 4;          // quarter-wave = row sub-group

    f32x4 acc[4][10] = {};

#define ISSUE(bufi, t)                                                        \
    do {                                                                      \
        if (aWave) {                                                          \
            _Pragma("unroll")                                                 \
            for (int j = 0; j < 4; ++j)                                       \
                async_copy16(pA + (size_t)(t) * ATILE + aoff + j * 1024,      \
                             (char*)&AsBuf[bufi][0] + aoff + j * 1024);       \
        } else {                                                              \
            _Pragma("unroll")                                                 \
            for (int j = 0; j < 5; ++j)                                       \
                async_copy16(pB + (size_t)(t) * BTILE + boff + j * 1024,      \
                             (char*)&BsBuf[bufi][0] + boff + j * 1024);       \
        }                                                                     \
    } while (0)

#define COMPUTE(bufi)                                                         \
    do {                                                                      \
        bf16x8_t a_[4];                                                       \
        _Pragma("unroll")                                                     \
        for (int mt = 0; mt < 4; ++mt)                                        \
            a_[mt] = *reinterpret_cast<const bf16x8_t*>(                      \
                &AsBuf[bufi][(wm + mt * 16 + l15) * BK + chnk]);              \
        _Pragma("unroll")                                                     \
        for (int nt = 0; nt < 10; ++nt) {                                     \
            bf16x8_t b_ = *reinterpret_cast<const bf16x8_t*>(                 \
                &BsBuf[bufi][(wn + nt * 16 + l15) * BK + chnk]);              \
            _Pragma("unroll")                                                 \
            for (int mt = 0; mt < 4; ++mt)                                    \
                acc[mt][nt] = __builtin_amdgcn_mfma_f32_16x16x32_bf16(        \
                    a_[mt], b_, acc[mt][nt], 0, 0, 0);                        \
        }                                                                     \
    } while (0)

#define WAITAB(na, nb_)                                                       \
    do {                                                                      \
        if (aWave) asm volatile("s_waitcnt vmcnt(" #na ")" ::: "memory");     \
        else       asm volatile("s_waitcnt vmcnt(" #nb_ ")" ::: "memory");    \
    } while (0)

    // Merged phase: compute tiles (t, t+1) from bufs (b0, b1); then issue
    // tiles (t+4, t+5) into the bufs just freed. 1 barrier pair / 2 K-tiles.
#define MPHASE(b0, b1, t)                                                     \
    do {                                                                      \
        WAITAB(8, 10);                                                        \
        __builtin_amdgcn_s_barrier();                                         \
        asm volatile("" ::: "memory");                                        \
        COMPUTE(b0);                                                          \
        asm volatile("" ::: "memory");                                        \
        COMPUTE(b1);                                                          \
        asm volatile("" ::: "memory");                                        \
        __builtin_amdgcn_s_barrier();                                         \
        ISSUE(b0, t + 4);                                                     \
        ISSUE(b1, t + 5);                                                     \
    } while (0)

    // prologue: tiles 0..3 -> bufs 0..3
    ISSUE(0, 0);
    ISSUE(1, 1);
    ISSUE(2, 2);
    ISSUE(3, 3);

    for (int i = 0; i < 63; ++i) {
        const int t = i * 4;
        MPHASE(0, 1, t);          // computes t,t+1;   issues t+4,t+5
        MPHASE(2, 3, t + 2);      // computes t+2,t+3; issues t+6,t+7
    }
    // tail: tiles 252..255 in bufs 0..3 (no further issues)
    WAITAB(8, 10);
    __builtin_amdgcn_s_barrier();
    asm volatile("" ::: "memory");
    COMPUTE(0);
    asm volatile("" ::: "memory");
    COMPUTE(1);
    asm volatile("" ::: "memory");
    __builtin_amdgcn_s_barrier();

    asm volatile("s_waitcnt vmcnt(0)" ::: "memory");
    __builtin_amdgcn_s_barrier();
    asm volatile("" ::: "memory");
    COMPUTE(2);
    asm volatile("" ::: "memory");
    COMPUTE(3);

    // ---- stage V for this block's 256 rows into the now-dead LDS ----------
    __syncthreads();   // all waves done reading AsBuf/BsBuf
    #pragma unroll
    for (int k = 0; k < 48; ++k) {
        const int e   = k * 512 + tid;           // 0..24575 (24576 = 2*256*48)
        const int hh  = e / 12288;               // uniform per k (12288=24*512)
        const int rem = e - hh * 12288;
        const int r   = rem / 48;
        const int c   = rem - r * 48;            // 0..47 = m*16 + j
        const int m   = c >> 4, j = c & 15;
        const float v = (hh ? V2 : V1)[(size_t)(m0 + r) * 48 + c];
        sV[((hh * 3 + m) * 256 + r) * 17 + j] = v;
    }
    __syncthreads();

    // epilogue: y = relu(g * (acc + b) / sqrt(1.001) + be), params fused.
    // inv columns -> out_inv directly; eq columns -> 16-lane butterfly
    // against sV, write out_eq (deletes Yeq round-trip + eqcomb kernel).
    const float RSQ = 0.9995003746877732f;
    #pragma unroll
    for (int nt = 0; nt < 10; ++nt) {
        const int gn = n0 + wn + nt * 16 + l15;
        if (gn < NINV) {
            const float bbp = b_inv[gn];
            const float gg  = g_inv[gn] * RSQ;
            const float bep = be_inv[gn];
            #pragma unroll
            for (int mt = 0; mt < 4; ++mt) {
                const int gmb = m0 + wm + mt * 16 + q * 4;
                #pragma unroll
                for (int rr = 0; rr < 4; ++rr) {
                    float y = fmaxf(gg * (acc[mt][nt][rr] + bbp) + bep, 0.0f);
                    out_inv[(size_t)(gmb + rr) * NINV + gn] = y;
                }
            }
        } else {
            const int e   = gn - NINV;
            const int hh  = e >> 10;             // head (uniform per nt)
            const int el  = e & 1023;
            const int uu  = el >> 4;             // unit (uniform per nt)
            const float bbp = b_eq[hh * NEQ + el];
            const float gg  = g_eq[hh * NEQ + el] * RSQ;
            const float bep = be_eq[hh * NEQ + el];
            #pragma unroll
            for (int mt = 0; mt < 4; ++mt) {
                const int rl0 = wm + mt * 16 + q * 4;   // local row base
                #pragma unroll
                for (int rr = 0; rr < 4; ++rr) {
                    const float y = fmaxf(gg * (acc[mt][nt][rr] + bbp) + bep, 0.0f);
                    const int rl = rl0 + rr;
                    #pragma unroll
                    for (int m = 0; m < 3; ++m) {
                        float p = y * sV[((hh * 3 + m) * 256 + rl) * 17 + l15];
                        p += __shfl_xor(p, 1);
                        p += __shfl_xor(p, 2);
                        p += __shfl_xor(p, 4);
                        p += __shfl_xor(p, 8);
                        if (l15 == 0)
                            out_eq[(size_t)(m0 + rl) * 384 + m * 128
                                   + hh * 64 + uu] = p;
                    }
                }
            }
        }
    }
#undef MPHASE
#undef WAITAB
#undef COMPUTE
#undef ISSUE
}

// ---------------------------------------------------------------------------
extern "C" void kernel_launch(void* const* d_in, const int* in_sizes, int n_in,
                              void* d_out, int out_size, void* d_ws, size_t ws_size,
                              hipStream_t stream) {
    const float* t1    = (const float*)d_in[0];
    const float* t2    = (const float*)d_in[1];
    const float* u1    = (const float*)d_in[2];
    const float* u2    = (const float*)d_in[3];
    const float* V1    = (const float*)d_in[4];
    const float* V2    = (const float*)d_in[5];
    const float* W_inv = (const float*)d_in[6];
    const float* b_inv = (const float*)d_in[7];
    const float* g_inv = (const float*)d_in[8];
    const float* be_inv= (const float*)d_in[9];
    const float* W_eq  = (const float*)d_in[10];
    const float* b_eq  = (const float*)d_in[11];
    const float* g_eq  = (const float*)d_in[12];
    const float* be_eq = (const float*)d_in[13];
    float* out = (float*)d_out;

    // workspace layout (bytes)
    char* ws = (char*)d_ws;
    __hip_bfloat16* feats = (__hip_bfloat16*)(ws);                       // 134,217,728 (packed)
    __hip_bfloat16* WT    = (__hip_bfloat16*)(ws + 134217728);           //  41,943,040 (packed)

    float* out_inv = out;                                  // [8192][512]
    float* out_eq  = out + (size_t)BROWS * NINV;           // [8192][3][128]

    hipLaunchKernelGGL(feats_kernel, dim3(BROWS / FROWS), dim3(256), 0, stream,
                       t1, t2, u1, u2, feats);
    hipLaunchKernelGGL(wt_kernel, dim3(NTOT / 32, KF / 32), dim3(256), 0, stream,
                       W_inv, W_eq, WT);
    hipLaunchKernelGGL(gemm_kernel, dim3((NTOT / BN) * (BROWS / BM)), dim3(512), 0, stream,
                       feats, WT, b_inv, g_inv, be_inv, b_eq, g_eq, be_eq,
                       V1, V2, out_inv, out_eq);
}

// Round 9
// 593.220 us; speedup vs baseline: 1.0177x; 1.0177x over previous
//
#include <hip/hip_runtime.h>
#include <hip/hip_bf16.h>

// Problem constants
#define BROWS 8192      // B*N = 8*1024
#define DDIM 3
#define CDIM 64
#define KF 8192         // F = 2*C*C
#define NINV 512
#define NEQ 1024        // per head
#define NTOT 2560       // 512 + 1024 + 1024
#define BAS 16
#define UEQ 64

// Packed-tile layouts (producers and GEMM agree):
//  A: tile (mb, kt) = 256 rows x 32 k bf16 = 16 KB at byte ((mb*256+kt) << 14)
//  B: tile (nb, kt) = 320 rows x 32 k bf16 = 20 KB at byte ((nb*256+kt) * 20480)
//  Within a tile, element (rloc, kk):
//    logical chunk lc = (kk>>3)&3, phys = (lc + (rloc>>1)) & 3  (bank swizzle)
//    byte = rloc*64 + phys*16 + (kk&7)*2
// Staging is a linear memcpy per tile.

typedef float f32x4 __attribute__((ext_vector_type(4)));
typedef __bf16 bf16x8_t __attribute__((ext_vector_type(8)));
typedef __bf16 bf16x4_t __attribute__((ext_vector_type(4)));

__device__ __forceinline__ void async_copy16(const void* g, void* l) {
    __builtin_amdgcn_global_load_lds(
        (__attribute__((address_space(1))) void*)(g),
        (__attribute__((address_space(3))) void*)(l), 16, 0, 0);
}

// ---------------------------------------------------------------------------
// Kernel 1: per-row l2norm + Gram blocks -> packed feats tiles [32][256][16KB]
// R4: 16 rows/block, wave-coalesced 1KB burst stores (R4 win: -36 us total).
// ---------------------------------------------------------------------------
#define FROWS 16
#define FSTRIDE 196

__global__ __launch_bounds__(256) void feats_kernel(
    const float* __restrict__ t1, const float* __restrict__ t2,
    const float* __restrict__ u1, const float* __restrict__ u2,
    __hip_bfloat16* __restrict__ feats)
{
    __shared__ float sT1[FROWS * FSTRIDE];
    __shared__ float sT2[FROWS * FSTRIDE];
    __shared__ float sU1[FROWS * FSTRIDE];
    __shared__ float sU2[FROWS * FSTRIDE];

    const int tid = threadIdx.x;
    const int r0  = blockIdx.x * FROWS;          // first row of this block

    // Phase 1: stage T,U (16 rows x 192 floats x 4 arrays), coalesced.
    #pragma unroll
    for (int k = 0; k < 12; ++k) {
        const int item = k * 256 + tid;          // < 3072
        const int r = item / 192, c = item - r * 192;
        const size_t g = (size_t)(r0 + r) * 192 + c;
        const int l = r * FSTRIDE + c;
        sT1[l] = t1[g];
        sT2[l] = t2[g];
        sU1[l] = u1[g];
        sU2[l] = u2[g];
    }
    __syncthreads();

    // Phase 2: l2-normalize U over d, per (row, head, c). 2048 items.
    #pragma unroll
    for (int k = 0; k < 8; ++k) {
        const int item = k * 256 + tid;          // < 2048
        const int r = item >> 7, rem = item & 127;
        const int h = rem >> 6, c = rem & 63;
        float* U = (h ? sU2 : sU1) + r * FSTRIDE;
        float sq = U[c] * U[c] + U[64 + c] * U[64 + c] + U[128 + c] * U[128 + c];
        float s = 1.0f / sqrtf(fmaxf(sq, 0.01f));
        U[c] *= s; U[64 + c] *= s; U[128 + c] *= s;
    }
    __syncthreads();

    // Phase 3: Gram compute + coalesced packed stores.
    const int w       = tid >> 6;        // wave 0..3 -> kt block
    const int lane    = tid & 63;
    const int r_local = lane >> 2;       // 0..15
    const int p       = lane & 3;        // phys chunk
    const int mb      = r0 >> 8;
    const int rloc0   = r0 & 255;
    const int rloc    = rloc0 + r_local;
    const int lc      = (p - (rloc >> 1)) & 3;   // invert phys swizzle
    const float* Tarr = (w >= 2 ? sT2 : sT1) + r_local * FSTRIDE;
    const float* Uarr = (w >= 2 ? sU2 : sU1) + r_local * FSTRIDE;

    char* dst = (char*)feats + (((size_t)(mb * 256 + w * 64)) << 14)
              + rloc0 * 64 + lane * 16;

    #pragma unroll 4
    for (int it = 0; it < 64; ++it) {
        const int kt = w * 64 + it;
        const int i  = (kt >> 1) & 63;
        const int jh = (kt & 1) * 32;
        const int j0 = jh + lc * 8;
        const float ti0 = Tarr[i], ti1 = Tarr[64 + i], ti2 = Tarr[128 + i];
        bf16x8_t vv;
        #pragma unroll
        for (int half = 0; half < 2; ++half) {
            const int j = j0 + half * 4;
            const float4 u0 = *reinterpret_cast<const float4*>(Uarr + j);
            const float4 u1_ = *reinterpret_cast<const float4*>(Uarr + 64 + j);
            const float4 u2_ = *reinterpret_cast<const float4*>(Uarr + 128 + j);
            vv[half * 4 + 0] = (__bf16)(ti0 * u0.x + ti1 * u1_.x + ti2 * u2_.x);
            vv[half * 4 + 1] = (__bf16)(ti0 * u0.y + ti1 * u1_.y + ti2 * u2_.y);
            vv[half * 4 + 2] = (__bf16)(ti0 * u0.z + ti1 * u1_.z + ti2 * u2_.z);
            vv[half * 4 + 3] = (__bf16)(ti0 * u0.w + ti1 * u1_.w + ti2 * u2_.w);
        }
        *reinterpret_cast<bf16x8_t*>(dst) = vv;   // 64 lanes x 16B = 1KB burst
        dst += 16384;
    }
}

// ---------------------------------------------------------------------------
// Kernel 2: transpose+convert W (K x N fp32) -> packed WT tiles [8][256][20KB]
// ---------------------------------------------------------------------------
__global__ __launch_bounds__(256) void wt_kernel(
    const float* __restrict__ W_inv, const float* __restrict__ W_eq,
    __hip_bfloat16* __restrict__ WT)
{
    __shared__ float tile[32][33];
    const int tid = threadIdx.x;
    const int tx = tid & 31;          // n within tile (load)
    const int ty = tid >> 5;          // 0..7
    const int n0 = blockIdx.x * 32;   // output column block (0..2559)
    const int k0 = blockIdx.y * 32;   // K block (0..8191)

    const float* src; int ldn, nl0;
    if (n0 < NINV)            { src = W_inv;                       ldn = NINV; nl0 = n0; }
    else if (n0 < NINV + NEQ) { src = W_eq;                        ldn = NEQ;  nl0 = n0 - NINV; }
    else                      { src = W_eq + (size_t)KF * NEQ;     ldn = NEQ;  nl0 = n0 - NINV - NEQ; }

    #pragma unroll
    for (int i = 0; i < 4; ++i) {
        int kl = ty + i * 8;
        tile[kl][tx] = src[(size_t)(k0 + kl) * ldn + nl0 + tx];
    }
    __syncthreads();
    // store phase: each thread packs 4 consecutive k for one n (8 B store)
    const int n_l = tid >> 3;         // 0..31
    const int k4  = (tid & 7) * 4;    // 0..28
    bf16x4_t v;
    #pragma unroll
    for (int q = 0; q < 4; ++q) v[q] = (__bf16)tile[k4 + q][n_l];

    const int n    = n0 + n_l;
    const int nb   = n / 320, rloc = n - nb * 320;
    const int kt   = k0 >> 5;
    const int lc   = (k4 >> 3) & 3, e = k4 & 7;
    const int phys = (lc + (rloc >> 1)) & 3;
    char* dst = (char*)WT + ((size_t)(nb * 256 + kt)) * 20480
              + rloc * 64 + phys * 16 + e * 2;
    *reinterpret_cast<bf16x4_t*>(dst) = v;
}

// ---------------------------------------------------------------------------
// Kernel 3: bf16 MFMA GEMM on packed tiles + FUSED eq-recombine epilogue.
// BM=256 x BN=320, 256 blocks (1/CU), 512 threads = 8 waves (4m x 2n).
// R5: eqcomb fused (deletes Yeq 67MB w + 67MB r + 4th kernel). R5's
//     per-thread shfl-butterfly cost +80us (1.77M bank-conflicts, serial
//     ds-pipe chains).
// R6: wave-local LDS transpose instead: stage y as sY[row][j] (stride 18 ->
//     2-way-free writes), lgkmcnt(0) (no barrier, same wave), lane=row reads
//     y + V (stride 17, 2-way-free) -> 3 dot16 per lane. No shfl chains.
// ---------------------------------------------------------------------------
#define BM 256
#define BN 320
#define BK 32
#define ATILE 16384
#define BTILE 20480

__global__ __launch_bounds__(512, 2) void gemm_kernel(
    const __hip_bfloat16* __restrict__ A,   // packed [32][256][16KB]
    const __hip_bfloat16* __restrict__ BT,  // packed [8][256][20KB]
    const float* __restrict__ b_inv, const float* __restrict__ g_inv,
    const float* __restrict__ be_inv,
    const float* __restrict__ b_eq,  const float* __restrict__ g_eq,
    const float* __restrict__ be_eq,
    const float* __restrict__ V1,   const float* __restrict__ V2,
    float* __restrict__ out_inv,            // d_out: [BROWS][NINV]
    float* __restrict__ out_eq)             // d_out: [BROWS][3][128]
{
    __shared__ alignas(16) char smem[147456];
    auto* AsBuf = reinterpret_cast<__hip_bfloat16(*)[BM * BK]>(smem);           // 4 x 16 KB
    auto* BsBuf = reinterpret_cast<__hip_bfloat16(*)[BN * BK]>(smem + 65536);   // 4 x 20 KB
    float* sV   = reinterpret_cast<float*>(smem);  // reused after last COMPUTE
    // sV: [head][m][row 0..255][17] floats = 104,448 B (gcd(17,32)=1 -> 2-way)
    // sY: per-wave [64 rows][18] floats, 8 waves = 36,864 B at offset 104,448
    float* sYbase = reinterpret_cast<float*>(smem + 104448);

    const int tid  = threadIdx.x;
    const int wave = tid >> 6;
    const int lane = tid & 63;
    const bool aWave = wave < 4;

    // 256 blocks: xcd = b%8 owns 4 contiguous m-stripes, n fastest.
    const int b    = blockIdx.x;
    const int xcd  = b & 7;
    const int slot = b >> 3;            // 0..31
    const int nb   = slot & 7;          // 0..7
    const int mb   = xcd * 4 + (slot >> 3);
    const int n0   = nb * BN;
    const int m0   = mb * BM;

    const char* pA = (const char*)A  + ((size_t)mb << 22);        // mb*4MB
    const char* pB = (const char*)BT + (size_t)nb * 256 * BTILE;  // nb*5MB

    // staging offsets (linear memcpy within a tile)
    const int aoff = wave * 4096 + lane * 16;         // waves 0-3
    const int boff = (wave - 4) * 5120 + lane * 16;   // waves 4-7

    // ds_read chunk swizzle (row-parity based, tile-term-independent)
    const int chnk = (((lane >> 4) + ((lane & 15) >> 1)) & 3) * 8;
    const int wm = (wave & 3) * 64;
    const int wn = (wave >> 2) * 160;
    const int l15 = lane & 15;
    const int q   = lane >> 4;          // quarter-wave = row sub-group

    f32x4 acc[4][10] = {};

#define ISSUE(bufi, t)                                                        \
    do {                                                                      \
        if (aWave) {                                                          \
            _Pragma("unroll")                                                 \
            for (int j = 0; j < 4; ++j)                                       \
                async_copy16(pA + (size_t)(t) * ATILE + aoff + j * 1024,      \
                             (char*)&AsBuf[bufi][0] + aoff + j * 1024);       \
        } else {                                                              \
            _Pragma("unroll")                                                 \
            for (int j = 0; j < 5; ++j)                                       \
                async_copy16(pB + (size_t)(t) * BTILE + boff + j * 1024,      \
                             (char*)&BsBuf[bufi][0] + boff + j * 1024);       \
        }                                                                     \
    } while (0)

#define COMPUTE(bufi)                                                         \
    do {                                                                      \
        bf16x8_t a_[4];                                                       \
        _Pragma("unroll")                                                     \
        for (int mt = 0; mt < 4; ++mt)                                        \
            a_[mt] = *reinterpret_cast<const bf16x8_t*>(                      \
                &AsBuf[bufi][(wm + mt * 16 + l15) * BK + chnk]);              \
        _Pragma("unroll")                                                     \
        for (int nt = 0; nt < 10; ++nt) {                                     \
            bf16x8_t b_ = *reinterpret_cast<const bf16x8_t*>(                 \
                &BsBuf[bufi][(wn + nt * 16 + l15) * BK + chnk]);              \
            _Pragma("unroll")                                                 \
            for (int mt = 0; mt < 4; ++mt)                                    \
                acc[mt][nt] = __builtin_amdgcn_mfma_f32_16x16x32_bf16(        \
                    a_[mt], b_, acc[mt][nt], 0, 0, 0);                        \
        }                                                                     \
    } while (0)

#define WAITAB(na, nb_)                                                       \
    do {                                                                      \
        if (aWave) asm volatile("s_waitcnt vmcnt(" #na ")" ::: "memory");     \
        else       asm volatile("s_waitcnt vmcnt(" #nb_ ")" ::: "memory");    \
    } while (0)

    // Merged phase: compute tiles (t, t+1) from bufs (b0, b1); then issue
    // tiles (t+4, t+5) into the bufs just freed. 1 barrier pair / 2 K-tiles.
#define MPHASE(b0, b1, t)                                                     \
    do {                                                                      \
        WAITAB(8, 10);                                                        \
        __builtin_amdgcn_s_barrier();                                         \
        asm volatile("" ::: "memory");                                        \
        COMPUTE(b0);                                                          \
        asm volatile("" ::: "memory");                                        \
        COMPUTE(b1);                                                          \
        asm volatile("" ::: "memory");                                        \
        __builtin_amdgcn_s_barrier();                                         \
        ISSUE(b0, t + 4);                                                     \
        ISSUE(b1, t + 5);                                                     \
    } while (0)

    // prologue: tiles 0..3 -> bufs 0..3
    ISSUE(0, 0);
    ISSUE(1, 1);
    ISSUE(2, 2);
    ISSUE(3, 3);

    for (int i = 0; i < 63; ++i) {
        const int t = i * 4;
        MPHASE(0, 1, t);          // computes t,t+1;   issues t+4,t+5
        MPHASE(2, 3, t + 2);      // computes t+2,t+3; issues t+6,t+7
    }
    // tail: tiles 252..255 in bufs 0..3 (no further issues)
    WAITAB(8, 10);
    __builtin_amdgcn_s_barrier();
    asm volatile("" ::: "memory");
    COMPUTE(0);
    asm volatile("" ::: "memory");
    COMPUTE(1);
    asm volatile("" ::: "memory");
    __builtin_amdgcn_s_barrier();

    asm volatile("s_waitcnt vmcnt(0)" ::: "memory");
    __builtin_amdgcn_s_barrier();
    asm volatile("" ::: "memory");
    COMPUTE(2);
    asm volatile("" ::: "memory");
    COMPUTE(3);

    // ---- stage V for this block's 256 rows into the now-dead LDS ----------
    __syncthreads();   // all waves done reading AsBuf/BsBuf
    #pragma unroll
    for (int k = 0; k < 48; ++k) {
        const int e   = k * 512 + tid;           // 0..24575 (24576 = 2*256*48)
        const int hh  = e / 12288;               // uniform per k (12288=24*512)
        const int rem = e - hh * 12288;
        const int r   = rem / 48;
        const int c   = rem - r * 48;            // 0..47 = m*16 + j
        const int m   = c >> 4, j = c & 15;
        const float v = (hh ? V2 : V1)[(size_t)(m0 + r) * 48 + c];
        sV[((hh * 3 + m) * 256 + r) * 17 + j] = v;
    }
    __syncthreads();

    // epilogue: y = relu(g * (acc + b) / sqrt(1.001) + be), params fused.
    // inv -> out_inv direct. eq -> wave-local LDS transpose + dot16 per lane.
    const float RSQ = 0.9995003746877732f;
    float* sY = sYbase + wave * (64 * 18);
    #pragma unroll
    for (int nt = 0; nt < 10; ++nt) {
        const int gn = n0 + wn + nt * 16 + l15;
        if (gn < NINV) {
            const float bbp = b_inv[gn];
            const float gg  = g_inv[gn] * RSQ;
            const float bep = be_inv[gn];
            #pragma unroll
            for (int mt = 0; mt < 4; ++mt) {
                const int gmb = m0 + wm + mt * 16 + q * 4;
                #pragma unroll
                for (int rr = 0; rr < 4; ++rr) {
                    float y = fmaxf(gg * (acc[mt][nt][rr] + bbp) + bep, 0.0f);
                    out_inv[(size_t)(gmb + rr) * NINV + gn] = y;
                }
            }
        } else {
            // scalar (lane-uniform) head/unit for this 16-col group
            const int e0  = n0 + wn + nt * 16 - NINV;   // >= 0, mult of 16
            const int hh  = e0 >> 10;
            const int uu  = (e0 & 1023) >> 4;
            const int el  = (e0 & 1023) + l15;
            const float bbp = b_eq[hh * NEQ + el];
            const float gg  = g_eq[hh * NEQ + el] * RSQ;
            const float bep = be_eq[hh * NEQ + el];
            // stage y: sY[row_local][j], row_local = mt*16+q*4+rr, j = l15
            #pragma unroll
            for (int mt = 0; mt < 4; ++mt) {
                #pragma unroll
                for (int rr = 0; rr < 4; ++rr) {
                    const float y = fmaxf(gg * (acc[mt][nt][rr] + bbp) + bep, 0.0f);
                    sY[(mt * 16 + q * 4 + rr) * 18 + l15] = y;
                }
            }
            asm volatile("s_waitcnt lgkmcnt(0)" ::: "memory");
            // lane = row; dot16 against V for m=0..2
            const int row = lane;               // 0..63 local
            const float* yrow = sY + row * 18;
            const f32x4 y0 = *reinterpret_cast<const f32x4*>(yrow);
            const f32x4 y1 = *reinterpret_cast<const f32x4*>(yrow + 4);
            const f32x4 y2 = *reinterpret_cast<const f32x4*>(yrow + 8);
            const f32x4 y3 = *reinterpret_cast<const f32x4*>(yrow + 12);
            #pragma unroll
            for (int m = 0; m < 3; ++m) {
                const float* vrow = sV + ((hh * 3 + m) * 256 + wm + row) * 17;
                const f32x4 v0 = *reinterpret_cast<const f32x4*>(vrow);
                const f32x4 v1 = *reinterpret_cast<const f32x4*>(vrow + 4);
                const f32x4 v2 = *reinterpret_cast<const f32x4*>(vrow + 8);
                const f32x4 v3 = *reinterpret_cast<const f32x4*>(vrow + 12);
                float s = y0[0]*v0[0] + y0[1]*v0[1] + y0[2]*v0[2] + y0[3]*v0[3]
                        + y1[0]*v1[0] + y1[1]*v1[1] + y1[2]*v1[2] + y1[3]*v1[3]
                        + y2[0]*v2[0] + y2[1]*v2[1] + y2[2]*v2[2] + y2[3]*v2[3]
                        + y3[0]*v3[0] + y3[1]*v3[1] + y3[2]*v3[2] + y3[3]*v3[3];
                out_eq[(size_t)(m0 + wm + row) * 384 + m * 128 + hh * 64 + uu] = s;
            }
            asm volatile("s_waitcnt lgkmcnt(0)" ::: "memory");  // sY reads done
        }                                                        // before reuse
    }
#undef MPHASE
#undef WAITAB
#undef COMPUTE
#undef ISSUE
}

// ---------------------------------------------------------------------------
extern "C" void kernel_launch(void* const* d_in, const int* in_sizes, int n_in,
                              void* d_out, int out_size, void* d_ws, size_t ws_size,
                              hipStream_t stream) {
    const float* t1    = (const float*)d_in[0];
    const float* t2    = (const float*)d_in[1];
    const float* u1    = (const float*)d_in[2];
    const float* u2    = (const float*)d_in[3];
    const float* V1    = (const float*)d_in[4];
    const float* V2    = (const float*)d_in[5];
    const float* W_inv = (const float*)d_in[6];
    const float* b_inv = (const float*)d_in[7];
    const float* g_inv = (const float*)d_in[8];
    const float* be_inv= (const float*)d_in[9];
    const float* W_eq  = (const float*)d_in[10];
    const float* b_eq  = (const float*)d_in[11];
    const float* g_eq  = (const float*)d_in[12];
    const float* be_eq = (const float*)d_in[13];
    float* out = (float*)d_out;

    // workspace layout (bytes)
    char* ws = (char*)d_ws;
    __hip_bfloat16* feats = (__hip_bfloat16*)(ws);                       // 134,217,728 (packed)
    __hip_bfloat16* WT    = (__hip_bfloat16*)(ws + 134217728);           //  41,943,040 (packed)

    float* out_inv = out;                                  // [8192][512]
    float* out_eq  = out + (size_t)BROWS * NINV;           // [8192][3][128]

    hipLaunchKernelGGL(feats_kernel, dim3(BROWS / FROWS), dim3(256), 0, stream,
                       t1, t2, u1, u2, feats);
    hipLaunchKernelGGL(wt_kernel, dim3(NTOT / 32, KF / 32), dim3(256), 0, stream,
                       W_inv, W_eq, WT);
    hipLaunchKernelGGL(gemm_kernel, dim3((NTOT / BN) * (BROWS / BM)), dim3(512), 0, stream,
                       feats, WT, b_inv, g_inv, be_inv, b_eq, g_eq, be_eq,
                       V1, V2, out_inv, out_eq);
}

// Round 10
// 542.978 us; speedup vs baseline: 1.1118x; 1.0925x over previous
//
#include <hip/hip_runtime.h>
#include <hip/hip_bf16.h>

// Problem constants
#define BROWS 8192      // B*N = 8*1024
#define DDIM 3
#define CDIM 64
#define KF 8192         // F = 2*C*C
#define NINV 512
#define NEQ 1024        // per head
#define NTOT 2560       // 512 + 1024 + 1024
#define BAS 16
#define UEQ 64

// Packed-tile layouts (producers and GEMM agree):
//  A: tile (mb, kt) = 256 rows x 32 k bf16 = 16 KB at byte ((mb*256+kt) << 14)
//  B: tile (nb, kt) = 320 rows x 32 k bf16 = 20 KB at byte ((nb*256+kt) * 20480)
//  Within a tile, element (rloc, kk):
//    logical chunk lc = (kk>>3)&3, phys = (lc + (rloc>>1)) & 3  (bank swizzle)
//    byte = rloc*64 + phys*16 + (kk&7)*2
// Staging is a linear memcpy per tile.

typedef float f32x4 __attribute__((ext_vector_type(4)));
typedef __bf16 bf16x8_t __attribute__((ext_vector_type(8)));
typedef __bf16 bf16x4_t __attribute__((ext_vector_type(4)));

__device__ __forceinline__ void async_copy16(const void* g, void* l) {
    __builtin_amdgcn_global_load_lds(
        (__attribute__((address_space(1))) void*)(g),
        (__attribute__((address_space(3))) void*)(l), 16, 0, 0);
}

// ---------------------------------------------------------------------------
// Kernel 1: per-row l2norm + Gram blocks -> packed feats tiles [32][256][16KB]
// R4: 16 rows/block, wave-coalesced 1KB burst stores (R4 win: -36 us total).
// ---------------------------------------------------------------------------
#define FROWS 16
#define FSTRIDE 196

__global__ __launch_bounds__(256) void feats_kernel(
    const float* __restrict__ t1, const float* __restrict__ t2,
    const float* __restrict__ u1, const float* __restrict__ u2,
    __hip_bfloat16* __restrict__ feats)
{
    __shared__ float sT1[FROWS * FSTRIDE];
    __shared__ float sT2[FROWS * FSTRIDE];
    __shared__ float sU1[FROWS * FSTRIDE];
    __shared__ float sU2[FROWS * FSTRIDE];

    const int tid = threadIdx.x;
    const int r0  = blockIdx.x * FROWS;          // first row of this block

    // Phase 1: stage T,U (16 rows x 192 floats x 4 arrays), coalesced.
    #pragma unroll
    for (int k = 0; k < 12; ++k) {
        const int item = k * 256 + tid;          // < 3072
        const int r = item / 192, c = item - r * 192;
        const size_t g = (size_t)(r0 + r) * 192 + c;
        const int l = r * FSTRIDE + c;
        sT1[l] = t1[g];
        sT2[l] = t2[g];
        sU1[l] = u1[g];
        sU2[l] = u2[g];
    }
    __syncthreads();

    // Phase 2: l2-normalize U over d, per (row, head, c). 2048 items.
    #pragma unroll
    for (int k = 0; k < 8; ++k) {
        const int item = k * 256 + tid;          // < 2048
        const int r = item >> 7, rem = item & 127;
        const int h = rem >> 6, c = rem & 63;
        float* U = (h ? sU2 : sU1) + r * FSTRIDE;
        float sq = U[c] * U[c] + U[64 + c] * U[64 + c] + U[128 + c] * U[128 + c];
        float s = 1.0f / sqrtf(fmaxf(sq, 0.01f));
        U[c] *= s; U[64 + c] *= s; U[128 + c] *= s;
    }
    __syncthreads();

    // Phase 3: Gram compute + coalesced packed stores.
    const int w       = tid >> 6;        // wave 0..3 -> kt block
    const int lane    = tid & 63;
    const int r_local = lane >> 2;       // 0..15
    const int p       = lane & 3;        // phys chunk
    const int mb      = r0 >> 8;
    const int rloc0   = r0 & 255;
    const int rloc    = rloc0 + r_local;
    const int lc      = (p - (rloc >> 1)) & 3;   // invert phys swizzle
    const float* Tarr = (w >= 2 ? sT2 : sT1) + r_local * FSTRIDE;
    const float* Uarr = (w >= 2 ? sU2 : sU1) + r_local * FSTRIDE;

    char* dst = (char*)feats + (((size_t)(mb * 256 + w * 64)) << 14)
              + rloc0 * 64 + lane * 16;

    #pragma unroll 4
    for (int it = 0; it < 64; ++it) {
        const int kt = w * 64 + it;
        const int i  = (kt >> 1) & 63;
        const int jh = (kt & 1) * 32;
        const int j0 = jh + lc * 8;
        const float ti0 = Tarr[i], ti1 = Tarr[64 + i], ti2 = Tarr[128 + i];
        bf16x8_t vv;
        #pragma unroll
        for (int half = 0; half < 2; ++half) {
            const int j = j0 + half * 4;
            const float4 u0 = *reinterpret_cast<const float4*>(Uarr + j);
            const float4 u1_ = *reinterpret_cast<const float4*>(Uarr + 64 + j);
            const float4 u2_ = *reinterpret_cast<const float4*>(Uarr + 128 + j);
            vv[half * 4 + 0] = (__bf16)(ti0 * u0.x + ti1 * u1_.x + ti2 * u2_.x);
            vv[half * 4 + 1] = (__bf16)(ti0 * u0.y + ti1 * u1_.y + ti2 * u2_.y);
            vv[half * 4 + 2] = (__bf16)(ti0 * u0.z + ti1 * u1_.z + ti2 * u2_.z);
            vv[half * 4 + 3] = (__bf16)(ti0 * u0.w + ti1 * u1_.w + ti2 * u2_.w);
        }
        *reinterpret_cast<bf16x8_t*>(dst) = vv;   // 64 lanes x 16B = 1KB burst
        dst += 16384;
    }
}

// ---------------------------------------------------------------------------
// Kernel 2: transpose+convert W (K x N fp32) -> packed WT tiles [8][256][20KB]
// R9 rewrite: block = 32 n x 64 k (grid 80 x 128). Old store phase wrote 8-B
// pieces with adjacent lanes 64 B apart (8x transaction amplification on
// 42 MB). Now: lane = (line n_l, phys p) emits one bf16x8 (16 B); a wave's
// 16 lines x 64 B = one contiguous 1024-B burst. LDS tile [64][33] fp32;
// store-phase read banks = (k+n) mod 32 -> uniform 2-way (free).
// ---------------------------------------------------------------------------
__global__ __launch_bounds__(256) void wt_kernel(
    const float* __restrict__ W_inv, const float* __restrict__ W_eq,
    __hip_bfloat16* __restrict__ WT)
{
    __shared__ float tile[64][33];
    const int tid = threadIdx.x;
    const int n0 = blockIdx.x * 32;   // output column block (0..2559)
    const int k0 = blockIdx.y * 64;   // K block (0..8191), 64-aligned

    const float* src; int ldn, nl0;
    if (n0 < NINV)            { src = W_inv;                       ldn = NINV; nl0 = n0; }
    else if (n0 < NINV + NEQ) { src = W_eq;                        ldn = NEQ;  nl0 = n0 - NINV; }
    else                      { src = W_eq + (size_t)KF * NEQ;     ldn = NEQ;  nl0 = n0 - NINV - NEQ; }

    // load: 64 k-rows x 32 n floats, coalesced 128-B row bursts
    {
        const int tx = tid & 31;          // n within tile
        const int ty = tid >> 5;          // 0..7
        #pragma unroll
        for (int i = 0; i < 8; ++i) {
            const int kl = ty + i * 8;    // 0..63
            tile[kl][tx] = src[(size_t)(k0 + kl) * ldn + nl0 + tx];
        }
    }
    __syncthreads();

    // store: thread t -> (kt_l = t>>7, n_l = (t&127)>>2, p = t&3)
    // wave (64 lanes) = 16 consecutive lines x 64 B = 1024-B contiguous burst
    const int kt_l = tid >> 7;            // 0..1
    const int rem  = tid & 127;
    const int n_l  = rem >> 2;            // 0..31
    const int p    = rem & 3;             // phys chunk

    const int n    = n0 + n_l;
    const int nb   = n / 320, rloc = n - nb * 320;
    const int kt_g = (k0 >> 5) + kt_l;
    const int lc   = (p - (rloc >> 1)) & 3;      // invert phys swizzle

    bf16x8_t v;
    #pragma unroll
    for (int e = 0; e < 8; ++e)
        v[e] = (__bf16)tile[kt_l * 32 + lc * 8 + e][n_l];

    char* dst = (char*)WT + ((size_t)(nb * 256 + kt_g)) * 20480
              + rloc * 64 + p * 16;
    *reinterpret_cast<bf16x8_t*>(dst) = v;
}

// ---------------------------------------------------------------------------
// Kernel 3: bf16 MFMA GEMM on packed tiles. BM=256 x BN=320, grid = exactly
// 256 blocks (1/CU, no tail). 512 threads = 8 waves (4m x 2n), wave tile
// 64x160. 4 LDS buffers (144 KB), static indices.
// Waves 0-3 stage A (4 x 16B/phase), waves 4-7 stage B (5/phase).
// History: setprio regressed (R2, -6%); merged 2-tile barrier windows
// neutral (R3, kept); eq-fusion regressed (R5/R6: latency-bound GEMM gains
// nothing from traffic cuts, epilogue serialization costs +57us) -> reverted
// to split pipeline (this version = R4's 546us config).
// ---------------------------------------------------------------------------
#define BM 256
#define BN 320
#define BK 32
#define ATILE 16384
#define BTILE 20480

__global__ __launch_bounds__(512, 2) void gemm_kernel(
    const __hip_bfloat16* __restrict__ A,   // packed [32][256][16KB]
    const __hip_bfloat16* __restrict__ BT,  // packed [8][256][20KB]
    const float* __restrict__ b_inv, const float* __restrict__ g_inv,
    const float* __restrict__ be_inv,
    const float* __restrict__ b_eq,  const float* __restrict__ g_eq,
    const float* __restrict__ be_eq,
    float* __restrict__ out_inv,            // d_out: [BROWS][NINV]
    float* __restrict__ Yeq)                // ws:    [BROWS][2048]
{
    __shared__ alignas(16) __hip_bfloat16 AsBuf[4][BM * BK];  // 4 x 16 KB
    __shared__ alignas(16) __hip_bfloat16 BsBuf[4][BN * BK];  // 4 x 20 KB

    const int tid  = threadIdx.x;
    const int wave = tid >> 6;
    const int lane = tid & 63;
    const bool aWave = wave < 4;

    // 256 blocks: xcd = b%8 owns 4 contiguous m-stripes, n fastest.
    const int b    = blockIdx.x;
    const int xcd  = b & 7;
    const int slot = b >> 3;            // 0..31
    const int nb   = slot & 7;          // 0..7
    const int mb   = xcd * 4 + (slot >> 3);
    const int n0   = nb * BN;
    const int m0   = mb * BM;

    const char* pA = (const char*)A  + ((size_t)mb << 22);        // mb*4MB
    const char* pB = (const char*)BT + (size_t)nb * 256 * BTILE;  // nb*5MB

    // staging offsets (linear memcpy within a tile)
    const int aoff = wave * 4096 + lane * 16;         // waves 0-3
    const int boff = (wave - 4) * 5120 + lane * 16;   // waves 4-7

    // ds_read chunk swizzle (row-parity based, tile-term-independent)
    const int chnk = (((lane >> 4) + ((lane & 15) >> 1)) & 3) * 8;
    const int wm = (wave & 3) * 64;
    const int wn = (wave >> 2) * 160;
    const int l15 = lane & 15;

    f32x4 acc[4][10] = {};

#define ISSUE(bufi, t)                                                        \
    do {                                                                      \
        if (aWave) {                                                          \
            _Pragma("unroll")                                                 \
            for (int j = 0; j < 4; ++j)                                       \
                async_copy16(pA + (size_t)(t) * ATILE + aoff + j * 1024,      \
                             (char*)&AsBuf[bufi][0] + aoff + j * 1024);       \
        } else {                                                              \
            _Pragma("unroll")                                                 \
            for (int j = 0; j < 5; ++j)                                       \
                async_copy16(pB + (size_t)(t) * BTILE + boff + j * 1024,      \
                             (char*)&BsBuf[bufi][0] + boff + j * 1024);       \
        }                                                                     \
    } while (0)

#define COMPUTE(bufi)                                                         \
    do {                                                                      \
        bf16x8_t a_[4];                                                       \
        _Pragma("unroll")                                                     \
        for (int mt = 0; mt < 4; ++mt)                                        \
            a_[mt] = *reinterpret_cast<const bf16x8_t*>(                      \
                &AsBuf[bufi][(wm + mt * 16 + l15) * BK + chnk]);              \
        _Pragma("unroll")                                                     \
        for (int nt = 0; nt < 10; ++nt) {                                     \
            bf16x8_t b_ = *reinterpret_cast<const bf16x8_t*>(                 \
                &BsBuf[bufi][(wn + nt * 16 + l15) * BK + chnk]);              \
            _Pragma("unroll")                                                 \
            for (int mt = 0; mt < 4; ++mt)                                    \
                acc[mt][nt] = __builtin_amdgcn_mfma_f32_16x16x32_bf16(        \
                    a_[mt], b_, acc[mt][nt], 0, 0, 0);                        \
        }                                                                     \
    } while (0)

#define WAITAB(na, nb_)                                                       \
    do {                                                                      \
        if (aWave) asm volatile("s_waitcnt vmcnt(" #na ")" ::: "memory");     \
        else       asm volatile("s_waitcnt vmcnt(" #nb_ ")" ::: "memory");    \
    } while (0)

    // Merged phase: compute tiles (t, t+1) from bufs (b0, b1); then issue
    // tiles (t+4, t+5) into the bufs just freed. 1 barrier pair / 2 K-tiles.
#define MPHASE(b0, b1, t)                                                     \
    do {                                                                      \
        WAITAB(8, 10);                                                        \
        __builtin_amdgcn_s_barrier();                                         \
        asm volatile("" ::: "memory");                                        \
        COMPUTE(b0);                                                          \
        asm volatile("" ::: "memory");                                        \
        COMPUTE(b1);                                                          \
        asm volatile("" ::: "memory");                                        \
        __builtin_amdgcn_s_barrier();                                         \
        ISSUE(b0, t + 4);                                                     \
        ISSUE(b1, t + 5);                                                     \
    } while (0)

    // prologue: tiles 0..3 -> bufs 0..3
    ISSUE(0, 0);
    ISSUE(1, 1);
    ISSUE(2, 2);
    ISSUE(3, 3);

    for (int i = 0; i < 63; ++i) {
        const int t = i * 4;
        MPHASE(0, 1, t);          // computes t,t+1;   issues t+4,t+5
        MPHASE(2, 3, t + 2);      // computes t+2,t+3; issues t+6,t+7
    }
    // tail: tiles 252..255 in bufs 0..3 (no further issues)
    WAITAB(8, 10);
    __builtin_amdgcn_s_barrier();
    asm volatile("" ::: "memory");
    COMPUTE(0);
    asm volatile("" ::: "memory");
    COMPUTE(1);
    asm volatile("" ::: "memory");
    __builtin_amdgcn_s_barrier();

    asm volatile("s_waitcnt vmcnt(0)" ::: "memory");
    __builtin_amdgcn_s_barrier();
    asm volatile("" ::: "memory");
    COMPUTE(2);
    asm volatile("" ::: "memory");
    COMPUTE(3);

    // epilogue: y = relu(g * (acc + b) / sqrt(1.001) + be), params fused
    const float RSQ = 0.9995003746877732f;
    #pragma unroll
    for (int nt = 0; nt < 10; ++nt) {
        const int gn = n0 + wn + nt * 16 + l15;
        float bbp, gg, bep;
        if (gn < NINV) {
            bbp = b_inv[gn]; gg = g_inv[gn]; bep = be_inv[gn];
        } else {
            const int e = gn - NINV, hh = e >> 10, nl = e & 1023;
            bbp = b_eq[hh * NEQ + nl]; gg = g_eq[hh * NEQ + nl]; bep = be_eq[hh * NEQ + nl];
        }
        gg *= RSQ;
        #pragma unroll
        for (int mt = 0; mt < 4; ++mt) {
            const int gmb = m0 + wm + mt * 16 + ((lane >> 4) << 2);
            #pragma unroll
            for (int rr = 0; rr < 4; ++rr) {
                float y = fmaxf(gg * (acc[mt][nt][rr] + bbp) + bep, 0.0f);
                const size_t gm = gmb + rr;
                if (gn < NINV) out_inv[gm * NINV + gn] = y;
                else           Yeq[gm * 2048 + (gn - NINV)] = y;
            }
        }
    }
#undef MPHASE
#undef WAITAB
#undef COMPUTE
#undef ISSUE
}

// ---------------------------------------------------------------------------
// Kernel 4: basis recombine
// ---------------------------------------------------------------------------
__global__ __launch_bounds__(128) void eqcomb_kernel(
    const float* __restrict__ Yeq,   // [BROWS][2048]
    const float* __restrict__ V1, const float* __restrict__ V2,
    float* __restrict__ out_eq)      // [BROWS][3][128]
{
    const int row = blockIdx.x;
    const int tid = threadIdx.x;     // 128
    __shared__ float sV[2][DDIM][BAS];
    if (tid < 96) {
        const int h = tid / 48, rem = tid % 48;
        const float* V = h ? V2 : V1;
        sV[h][rem / BAS][rem % BAS] = V[(size_t)row * (DDIM * BAS) + rem];
    }
    __syncthreads();
    const int l = tid >> 6, u = tid & 63;
    const float4* y4 = reinterpret_cast<const float4*>(
        Yeq + (size_t)row * 2048 + l * 1024 + u * BAS);
    float a0 = 0.f, a1 = 0.f, a2 = 0.f;
    #pragma unroll
    for (int q = 0; q < 4; ++q) {
        float4 w = y4[q];
        const float* v0 = sV[l][0] + q * 4;
        const float* v1 = sV[l][1] + q * 4;
        const float* v2 = sV[l][2] + q * 4;
        a0 += w.x * v0[0] + w.y * v0[1] + w.z * v0[2] + w.w * v0[3];
        a1 += w.x * v1[0] + w.y * v1[1] + w.z * v1[2] + w.w * v1[3];
        a2 += w.x * v2[0] + w.y * v2[1] + w.z * v2[2] + w.w * v2[3];
    }
    float* o = out_eq + (size_t)row * (DDIM * 128);
    o[0 * 128 + l * 64 + u] = a0;
    o[1 * 128 + l * 64 + u] = a1;
    o[2 * 128 + l * 64 + u] = a2;
}

// ---------------------------------------------------------------------------
extern "C" void kernel_launch(void* const* d_in, const int* in_sizes, int n_in,
                              void* d_out, int out_size, void* d_ws, size_t ws_size,
                              hipStream_t stream) {
    const float* t1    = (const float*)d_in[0];
    const float* t2    = (const float*)d_in[1];
    const float* u1    = (const float*)d_in[2];
    const float* u2    = (const float*)d_in[3];
    const float* V1    = (const float*)d_in[4];
    const float* V2    = (const float*)d_in[5];
    const float* W_inv = (const float*)d_in[6];
    const float* b_inv = (const float*)d_in[7];
    const float* g_inv = (const float*)d_in[8];
    const float* be_inv= (const float*)d_in[9];
    const float* W_eq  = (const float*)d_in[10];
    const float* b_eq  = (const float*)d_in[11];
    const float* g_eq  = (const float*)d_in[12];
    const float* be_eq = (const float*)d_in[13];
    float* out = (float*)d_out;

    // workspace layout (bytes)
    char* ws = (char*)d_ws;
    __hip_bfloat16* feats = (__hip_bfloat16*)(ws);                       // 134,217,728 (packed)
    __hip_bfloat16* WT    = (__hip_bfloat16*)(ws + 134217728);           //  41,943,040 (packed)
    float*          Yeq   = (float*)(ws + 176160768);                    //  67,108,864

    float* out_inv = out;                                  // [8192][512]
    float* out_eq  = out + (size_t)BROWS * NINV;           // [8192][3][128]

    hipLaunchKernelGGL(feats_kernel, dim3(BROWS / FROWS), dim3(256), 0, stream,
                       t1, t2, u1, u2, feats);
    hipLaunchKernelGGL(wt_kernel, dim3(NTOT / 32, KF / 64), dim3(256), 0, stream,
                       W_inv, W_eq, WT);
    hipLaunchKernelGGL(gemm_kernel, dim3((NTOT / BN) * (BROWS / BM)), dim3(512), 0, stream,
                       feats, WT, b_inv, g_inv, be_inv, b_eq, g_eq, be_eq,
                       out_inv, Yeq);
    hipLaunchKernelGGL(eqcomb_kernel, dim3(BROWS), dim3(128), 0, stream,
                       Yeq, V1, V2, out_eq);
}

// Round 11
// 523.904 us; speedup vs baseline: 1.1523x; 1.0364x over previous
//
#include <hip/hip_runtime.h>
#include <hip/hip_bf16.h>

// Problem constants
#define BROWS 8192      // B*N = 8*1024
#define DDIM 3
#define CDIM 64
#define KF 8192         // F = 2*C*C
#define NINV 512
#define NEQ 1024        // per head
#define NTOT 2560       // 512 + 1024 + 1024
#define BAS 16
#define UEQ 64

// Packed-tile layouts (producers and GEMM agree):
//  A: tile (mb, kt) = 256 rows x 32 k bf16 = 16 KB at byte ((mb*256+kt) << 14)
//  B: tile (nb, kt) = 320 rows x 32 k bf16 = 20 KB at byte ((nb*256+kt) * 20480)
//  Within a tile, element (rloc, kk):
//    logical chunk lc = (kk>>3)&3, phys = (lc + (rloc>>1)) & 3  (bank swizzle)
//    byte = rloc*64 + phys*16 + (kk&7)*2
//  GEMM consumes 128-row (A) / 160-row (B) HALVES of packed tiles; the phys
//  swizzle is half-invariant (128,160 ≡ 0 mod 4 after >>1).

typedef float f32x4 __attribute__((ext_vector_type(4)));
typedef __bf16 bf16x8_t __attribute__((ext_vector_type(8)));
typedef __bf16 bf16x4_t __attribute__((ext_vector_type(4)));

__device__ __forceinline__ void async_copy16(const void* g, void* l) {
    __builtin_amdgcn_global_load_lds(
        (__attribute__((address_space(1))) void*)(g),
        (__attribute__((address_space(3))) void*)(l), 16, 0, 0);
}

// ---------------------------------------------------------------------------
// Kernel 1: per-row l2norm + Gram blocks -> packed feats tiles [32][256][16KB]
// R4: 16 rows/block, wave-coalesced 1KB burst stores (R4 win: -36 us total).
// ---------------------------------------------------------------------------
#define FROWS 16
#define FSTRIDE 196

__global__ __launch_bounds__(256) void feats_kernel(
    const float* __restrict__ t1, const float* __restrict__ t2,
    const float* __restrict__ u1, const float* __restrict__ u2,
    __hip_bfloat16* __restrict__ feats)
{
    __shared__ float sT1[FROWS * FSTRIDE];
    __shared__ float sT2[FROWS * FSTRIDE];
    __shared__ float sU1[FROWS * FSTRIDE];
    __shared__ float sU2[FROWS * FSTRIDE];

    const int tid = threadIdx.x;
    const int r0  = blockIdx.x * FROWS;          // first row of this block

    // Phase 1: stage T,U (16 rows x 192 floats x 4 arrays), coalesced.
    #pragma unroll
    for (int k = 0; k < 12; ++k) {
        const int item = k * 256 + tid;          // < 3072
        const int r = item / 192, c = item - r * 192;
        const size_t g = (size_t)(r0 + r) * 192 + c;
        const int l = r * FSTRIDE + c;
        sT1[l] = t1[g];
        sT2[l] = t2[g];
        sU1[l] = u1[g];
        sU2[l] = u2[g];
    }
    __syncthreads();

    // Phase 2: l2-normalize U over d, per (row, head, c). 2048 items.
    #pragma unroll
    for (int k = 0; k < 8; ++k) {
        const int item = k * 256 + tid;          // < 2048
        const int r = item >> 7, rem = item & 127;
        const int h = rem >> 6, c = rem & 63;
        float* U = (h ? sU2 : sU1) + r * FSTRIDE;
        float sq = U[c] * U[c] + U[64 + c] * U[64 + c] + U[128 + c] * U[128 + c];
        float s = 1.0f / sqrtf(fmaxf(sq, 0.01f));
        U[c] *= s; U[64 + c] *= s; U[128 + c] *= s;
    }
    __syncthreads();

    // Phase 3: Gram compute + coalesced packed stores.
    const int w       = tid >> 6;        // wave 0..3 -> kt block
    const int lane    = tid & 63;
    const int r_local = lane >> 2;       // 0..15
    const int p       = lane & 3;        // phys chunk
    const int mb      = r0 >> 8;
    const int rloc0   = r0 & 255;
    const int rloc    = rloc0 + r_local;
    const int lc      = (p - (rloc >> 1)) & 3;   // invert phys swizzle
    const float* Tarr = (w >= 2 ? sT2 : sT1) + r_local * FSTRIDE;
    const float* Uarr = (w >= 2 ? sU2 : sU1) + r_local * FSTRIDE;

    char* dst = (char*)feats + (((size_t)(mb * 256 + w * 64)) << 14)
              + rloc0 * 64 + lane * 16;

    #pragma unroll 4
    for (int it = 0; it < 64; ++it) {
        const int kt = w * 64 + it;
        const int i  = (kt >> 1) & 63;
        const int jh = (kt & 1) * 32;
        const int j0 = jh + lc * 8;
        const float ti0 = Tarr[i], ti1 = Tarr[64 + i], ti2 = Tarr[128 + i];
        bf16x8_t vv;
        #pragma unroll
        for (int half = 0; half < 2; ++half) {
            const int j = j0 + half * 4;
            const float4 u0 = *reinterpret_cast<const float4*>(Uarr + j);
            const float4 u1_ = *reinterpret_cast<const float4*>(Uarr + 64 + j);
            const float4 u2_ = *reinterpret_cast<const float4*>(Uarr + 128 + j);
            vv[half * 4 + 0] = (__bf16)(ti0 * u0.x + ti1 * u1_.x + ti2 * u2_.x);
            vv[half * 4 + 1] = (__bf16)(ti0 * u0.y + ti1 * u1_.y + ti2 * u2_.y);
            vv[half * 4 + 2] = (__bf16)(ti0 * u0.z + ti1 * u1_.z + ti2 * u2_.z);
            vv[half * 4 + 3] = (__bf16)(ti0 * u0.w + ti1 * u1_.w + ti2 * u2_.w);
        }
        *reinterpret_cast<bf16x8_t*>(dst) = vv;   // 64 lanes x 16B = 1KB burst
        dst += 16384;
    }
}

// ---------------------------------------------------------------------------
// Kernel 2: transpose+convert W (K x N fp32) -> packed WT tiles [8][256][20KB]
// R9: block = 32 n x 64 k; wave store = one contiguous 1024-B burst.
// ---------------------------------------------------------------------------
__global__ __launch_bounds__(256) void wt_kernel(
    const float* __restrict__ W_inv, const float* __restrict__ W_eq,
    __hip_bfloat16* __restrict__ WT)
{
    __shared__ float tile[64][33];
    const int tid = threadIdx.x;
    const int n0 = blockIdx.x * 32;   // output column block (0..2559)
    const int k0 = blockIdx.y * 64;   // K block (0..8191), 64-aligned

    const float* src; int ldn, nl0;
    if (n0 < NINV)            { src = W_inv;                       ldn = NINV; nl0 = n0; }
    else if (n0 < NINV + NEQ) { src = W_eq;                        ldn = NEQ;  nl0 = n0 - NINV; }
    else                      { src = W_eq + (size_t)KF * NEQ;     ldn = NEQ;  nl0 = n0 - NINV - NEQ; }

    // load: 64 k-rows x 32 n floats, coalesced 128-B row bursts
    {
        const int tx = tid & 31;          // n within tile
        const int ty = tid >> 5;          // 0..7
        #pragma unroll
        for (int i = 0; i < 8; ++i) {
            const int kl = ty + i * 8;    // 0..63
            tile[kl][tx] = src[(size_t)(k0 + kl) * ldn + nl0 + tx];
        }
    }
    __syncthreads();

    // store: thread t -> (kt_l = t>>7, n_l = (t&127)>>2, p = t&3)
    const int kt_l = tid >> 7;            // 0..1
    const int rem  = tid & 127;
    const int n_l  = rem >> 2;            // 0..31
    const int p    = rem & 3;             // phys chunk

    const int n    = n0 + n_l;
    const int nb   = n / 320, rloc = n - nb * 320;
    const int kt_g = (k0 >> 5) + kt_l;
    const int lc   = (p - (rloc >> 1)) & 3;      // invert phys swizzle

    bf16x8_t v;
    #pragma unroll
    for (int e = 0; e < 8; ++e)
        v[e] = (__bf16)tile[kt_l * 32 + lc * 8 + e][n_l];

    char* dst = (char*)WT + ((size_t)(nb * 256 + kt_g)) * 20480
              + rloc * 64 + p * 16;
    *reinterpret_cast<bf16x8_t*>(dst) = v;
}

// ---------------------------------------------------------------------------
// Kernel 3: bf16 MFMA GEMM on packed tiles.
// R10: BM 256->128, BN 320->160, LDS 144->72 KB => 2 blocks/CU (was 1),
//      grid 1024 (2 resident rounds). Rationale: MfmaUtil pinned 37-39%
//      across all schedule variants at 1 lockstep block/CU; a second
//      resident block overlaps barrier/vmcnt stalls with compute.
//      Pipeline structure unchanged (4 bufs, merged 2-tile phases,
//      prefetch distance 2, counted vmcnt). All 8 waves stage both A and B
//      (A: 1 copy/thread; B: 1 copy/thread + 2nd copy on waves 0-1).
// History: setprio -6% (R2); barrier-merge neutral (R3, kept); eq-fusion
//      reverted (R5/R6: latency-bound GEMM gains nothing from traffic cuts).
// ---------------------------------------------------------------------------
#define BM 128
#define BN 160
#define BK 32
#define ATILE 16384     // stride between consecutive-kt packed A tiles
#define BTILE 20480     // stride between consecutive-kt packed B tiles
#define AHALF 8192      // bytes of one 128-row A half-tile
#define BHALF 10240     // bytes of one 160-row B half-tile

__global__ __launch_bounds__(512, 4) void gemm_kernel(
    const __hip_bfloat16* __restrict__ A,   // packed [32][256][16KB]
    const __hip_bfloat16* __restrict__ BT,  // packed [8][256][20KB]
    const float* __restrict__ b_inv, const float* __restrict__ g_inv,
    const float* __restrict__ be_inv,
    const float* __restrict__ b_eq,  const float* __restrict__ g_eq,
    const float* __restrict__ be_eq,
    float* __restrict__ out_inv,            // d_out: [BROWS][NINV]
    float* __restrict__ Yeq)                // ws:    [BROWS][2048]
{
    __shared__ alignas(16) __hip_bfloat16 AsBuf[4][BM * BK];  // 4 x 8 KB
    __shared__ alignas(16) __hip_bfloat16 BsBuf[4][BN * BK];  // 4 x 10 KB

    const int tid  = threadIdx.x;
    const int wave = tid >> 6;
    const int lane = tid & 63;
    const bool loWave = wave < 2;       // waves 0-1 carry the extra B copy

    // 1024 blocks: xcd = b%8 owns 8 contiguous M-stripes, N fastest.
    const int b    = blockIdx.x;
    const int xcd  = b & 7;
    const int slot = b >> 3;            // 0..127
    const int N    = slot & 15;         // 0..15 (n-block, 160 cols)
    const int M    = xcd * 8 + (slot >> 4);   // 0..63 (m-block, 128 rows)
    const int n0   = N * BN;
    const int m0   = M * BM;

    const char* pA = (const char*)A  + (size_t)(M >> 1) * 256 * ATILE
                   + (size_t)(M & 1) * AHALF;
    const char* pB = (const char*)BT + (size_t)(N >> 1) * 256 * BTILE
                   + (size_t)(N & 1) * BHALF;

    const int off16 = tid * 16;         // linear staging offset

    // ds_read chunk swizzle (row-parity based, half-tile invariant)
    const int chnk = (((lane >> 4) + ((lane & 15) >> 1)) & 3) * 8;
    const int wm = (wave & 3) * 32;     // 2 mt of 16 rows
    const int wn = (wave >> 2) * 80;    // 5 nt of 16 cols
    const int l15 = lane & 15;

    f32x4 acc[2][5] = {};

#define ISSUE(bufi, t)                                                        \
    do {                                                                      \
        async_copy16(pA + (size_t)(t) * ATILE + off16,                        \
                     (char*)&AsBuf[bufi][0] + off16);                         \
        async_copy16(pB + (size_t)(t) * BTILE + off16,                        \
                     (char*)&BsBuf[bufi][0] + off16);                         \
        if (loWave)                                                           \
            async_copy16(pB + (size_t)(t) * BTILE + 8192 + off16,             \
                         (char*)&BsBuf[bufi][0] + 8192 + off16);              \
    } while (0)

#define COMPUTE(bufi)                                                         \
    do {                                                                      \
        bf16x8_t a_[2];                                                       \
        _Pragma("unroll")                                                     \
        for (int mt = 0; mt < 2; ++mt)                                        \
            a_[mt] = *reinterpret_cast<const bf16x8_t*>(                      \
                &AsBuf[bufi][(wm + mt * 16 + l15) * BK + chnk]);              \
        _Pragma("unroll")                                                     \
        for (int nt = 0; nt < 5; ++nt) {                                      \
            bf16x8_t b_ = *reinterpret_cast<const bf16x8_t*>(                 \
                &BsBuf[bufi][(wn + nt * 16 + l15) * BK + chnk]);              \
            _Pragma("unroll")                                                 \
            for (int mt = 0; mt < 2; ++mt)                                    \
                acc[mt][nt] = __builtin_amdgcn_mfma_f32_16x16x32_bf16(        \
                    a_[mt], b_, acc[mt][nt], 0, 0, 0);                        \
        }                                                                     \
    } while (0)

    // per-thread copies/tile: loWave 3, else 2. Wait for 2 tiles in flight.
#define WAITAB(na, nb_)                                                       \
    do {                                                                      \
        if (loWave) asm volatile("s_waitcnt vmcnt(" #na ")" ::: "memory");    \
        else        asm volatile("s_waitcnt vmcnt(" #nb_ ")" ::: "memory");   \
    } while (0)

    // Merged phase: compute tiles (t, t+1) from bufs (b0, b1); then issue
    // tiles (t+4, t+5) into the bufs just freed. 1 barrier pair / 2 K-tiles.
#define MPHASE(b0, b1, t)                                                     \
    do {                                                                      \
        WAITAB(6, 4);                                                         \
        __builtin_amdgcn_s_barrier();                                         \
        asm volatile("" ::: "memory");                                        \
        COMPUTE(b0);                                                          \
        asm volatile("" ::: "memory");                                        \
        COMPUTE(b1);                                                          \
        asm volatile("" ::: "memory");                                        \
        __builtin_amdgcn_s_barrier();                                         \
        ISSUE(b0, t + 4);                                                     \
        ISSUE(b1, t + 5);                                                     \
    } while (0)

    // prologue: tiles 0..3 -> bufs 0..3
    ISSUE(0, 0);
    ISSUE(1, 1);
    ISSUE(2, 2);
    ISSUE(3, 3);

    for (int i = 0; i < 63; ++i) {
        const int t = i * 4;
        MPHASE(0, 1, t);          // computes t,t+1;   issues t+4,t+5
        MPHASE(2, 3, t + 2);      // computes t+2,t+3; issues t+6,t+7
    }
    // tail: tiles 252..255 in bufs 0..3 (no further issues)
    WAITAB(6, 4);
    __builtin_amdgcn_s_barrier();
    asm volatile("" ::: "memory");
    COMPUTE(0);
    asm volatile("" ::: "memory");
    COMPUTE(1);
    asm volatile("" ::: "memory");
    __builtin_amdgcn_s_barrier();

    asm volatile("s_waitcnt vmcnt(0)" ::: "memory");
    __builtin_amdgcn_s_barrier();
    asm volatile("" ::: "memory");
    COMPUTE(2);
    asm volatile("" ::: "memory");
    COMPUTE(3);

    // epilogue: y = relu(g * (acc + b) / sqrt(1.001) + be), params fused
    const float RSQ = 0.9995003746877732f;
    #pragma unroll
    for (int nt = 0; nt < 5; ++nt) {
        const int gn = n0 + wn + nt * 16 + l15;
        float bbp, gg, bep;
        if (gn < NINV) {
            bbp = b_inv[gn]; gg = g_inv[gn]; bep = be_inv[gn];
        } else {
            const int e = gn - NINV, hh = e >> 10, nl = e & 1023;
            bbp = b_eq[hh * NEQ + nl]; gg = g_eq[hh * NEQ + nl]; bep = be_eq[hh * NEQ + nl];
        }
        gg *= RSQ;
        #pragma unroll
        for (int mt = 0; mt < 2; ++mt) {
            const int gmb = m0 + wm + mt * 16 + ((lane >> 4) << 2);
            #pragma unroll
            for (int rr = 0; rr < 4; ++rr) {
                float y = fmaxf(gg * (acc[mt][nt][rr] + bbp) + bep, 0.0f);
                const size_t gm = gmb + rr;
                if (gn < NINV) out_inv[gm * NINV + gn] = y;
                else           Yeq[gm * 2048 + (gn - NINV)] = y;
            }
        }
    }
#undef MPHASE
#undef WAITAB
#undef COMPUTE
#undef ISSUE
}

// ---------------------------------------------------------------------------
// Kernel 4: basis recombine
// ---------------------------------------------------------------------------
__global__ __launch_bounds__(128) void eqcomb_kernel(
    const float* __restrict__ Yeq,   // [BROWS][2048]
    const float* __restrict__ V1, const float* __restrict__ V2,
    float* __restrict__ out_eq)      // [BROWS][3][128]
{
    const int row = blockIdx.x;
    const int tid = threadIdx.x;     // 128
    __shared__ float sV[2][DDIM][BAS];
    if (tid < 96) {
        const int h = tid / 48, rem = tid % 48;
        const float* V = h ? V2 : V1;
        sV[h][rem / BAS][rem % BAS] = V[(size_t)row * (DDIM * BAS) + rem];
    }
    __syncthreads();
    const int l = tid >> 6, u = tid & 63;
    const float4* y4 = reinterpret_cast<const float4*>(
        Yeq + (size_t)row * 2048 + l * 1024 + u * BAS);
    float a0 = 0.f, a1 = 0.f, a2 = 0.f;
    #pragma unroll
    for (int q = 0; q < 4; ++q) {
        float4 w = y4[q];
        const float* v0 = sV[l][0] + q * 4;
        const float* v1 = sV[l][1] + q * 4;
        const float* v2 = sV[l][2] + q * 4;
        a0 += w.x * v0[0] + w.y * v0[1] + w.z * v0[2] + w.w * v0[3];
        a1 += w.x * v1[0] + w.y * v1[1] + w.z * v1[2] + w.w * v1[3];
        a2 += w.x * v2[0] + w.y * v2[1] + w.z * v2[2] + w.w * v2[3];
    }
    float* o = out_eq + (size_t)row * (DDIM * 128);
    o[0 * 128 + l * 64 + u] = a0;
    o[1 * 128 + l * 64 + u] = a1;
    o[2 * 128 + l * 64 + u] = a2;
}

// ---------------------------------------------------------------------------
extern "C" void kernel_launch(void* const* d_in, const int* in_sizes, int n_in,
                              void* d_out, int out_size, void* d_ws, size_t ws_size,
                              hipStream_t stream) {
    const float* t1    = (const float*)d_in[0];
    const float* t2    = (const float*)d_in[1];
    const float* u1    = (const float*)d_in[2];
    const float* u2    = (const float*)d_in[3];
    const float* V1    = (const float*)d_in[4];
    const float* V2    = (const float*)d_in[5];
    const float* W_inv = (const float*)d_in[6];
    const float* b_inv = (const float*)d_in[7];
    const float* g_inv = (const float*)d_in[8];
    const float* be_inv= (const float*)d_in[9];
    const float* W_eq  = (const float*)d_in[10];
    const float* b_eq  = (const float*)d_in[11];
    const float* g_eq  = (const float*)d_in[12];
    const float* be_eq = (const float*)d_in[13];
    float* out = (float*)d_out;

    // workspace layout (bytes)
    char* ws = (char*)d_ws;
    __hip_bfloat16* feats = (__hip_bfloat16*)(ws);                       // 134,217,728 (packed)
    __hip_bfloat16* WT    = (__hip_bfloat16*)(ws + 134217728);           //  41,943,040 (packed)
    float*          Yeq   = (float*)(ws + 176160768);                    //  67,108,864

    float* out_inv = out;                                  // [8192][512]
    float* out_eq  = out + (size_t)BROWS * NINV;           // [8192][3][128]

    hipLaunchKernelGGL(feats_kernel, dim3(BROWS / FROWS), dim3(256), 0, stream,
                       t1, t2, u1, u2, feats);
    hipLaunchKernelGGL(wt_kernel, dim3(NTOT / 32, KF / 64), dim3(256), 0, stream,
                       W_inv, W_eq, WT);
    hipLaunchKernelGGL(gemm_kernel, dim3((NTOT / BN) * (BROWS / BM)), dim3(512), 0, stream,
                       feats, WT, b_inv, g_inv, be_inv, b_eq, g_eq, be_eq,
                       out_inv, Yeq);
    hipLaunchKernelGGL(eqcomb_kernel, dim3(BROWS), dim3(128), 0, stream,
                       Yeq, V1, V2, out_eq);
}